// Round 1
// baseline (865.986 us; speedup 1.0000x reference)
//
#include <hip/hip_runtime.h>
#include <hip/hip_bf16.h>
#include <math.h>

// Problem constants (reference: N=8192, H=2048, E=8, K=2, CF=1.25)
#define NTOK 8192
#define HDIM 2048
#define NEXP 8
#define TOPK 2
#define CAP  1280            // ceil(1.25 * 8192 / 8)
#define FF   4096            // 2*H

typedef float  f32x4  __attribute__((ext_vector_type(4)));
typedef __bf16 bf16x8 __attribute__((ext_vector_type(8)));

__device__ __forceinline__ ushort f2bf(float f) {
    union { float f; unsigned u; } c; c.f = f;
    unsigned u = c.u;
    unsigned r = (u + 0x7FFFu + ((u >> 16) & 1u)) >> 16;   // RNE
    return (ushort)r;
}
__device__ __forceinline__ float bf2f(ushort h) {
    union { unsigned u; float f; } c; c.u = ((unsigned)h) << 16;
    return c.f;
}

// ---------------- tokens f32 -> bf16 ----------------
__global__ void k_convert(const float* __restrict__ src, ushort* __restrict__ dst) {
    int i = (blockIdx.x * 256 + threadIdx.x) * 8;
    float4 a = *(const float4*)(src + i);
    float4 b = *(const float4*)(src + i + 4);
    uint4 o;
    o.x = (unsigned)f2bf(a.x) | ((unsigned)f2bf(a.y) << 16);
    o.y = (unsigned)f2bf(a.z) | ((unsigned)f2bf(a.w) << 16);
    o.z = (unsigned)f2bf(b.x) | ((unsigned)f2bf(b.y) << 16);
    o.w = (unsigned)f2bf(b.z) | ((unsigned)f2bf(b.w) << 16);
    *(uint4*)(dst + i) = o;
}

// ---------------- router: logits (f64 accum), top-2, softmax ----------------
__global__ void k_router(const float* __restrict__ tokens, const float* __restrict__ Wr,
                         const float* __restrict__ br, int* __restrict__ eids,
                         float* __restrict__ probs) {
    int wave = threadIdx.x >> 6, lane = threadIdx.x & 63;
    int t = blockIdx.x * 4 + wave;
    const float* tp = tokens + (size_t)t * HDIM;
    double acc[NEXP];
    #pragma unroll
    for (int e = 0; e < NEXP; ++e) acc[e] = 0.0;
    for (int j = 0; j < HDIM / 64; ++j) {
        float x = tp[j * 64 + lane];
        #pragma unroll
        for (int e = 0; e < NEXP; ++e)
            acc[e] += (double)x * (double)Wr[e * HDIM + j * 64 + lane];
    }
    #pragma unroll
    for (int e = 0; e < NEXP; ++e) {
        #pragma unroll
        for (int off = 32; off; off >>= 1) acc[e] += __shfl_xor(acc[e], off, 64);
    }
    if (lane == 0) {
        float lg[NEXP];
        #pragma unroll
        for (int e = 0; e < NEXP; ++e) lg[e] = (float)acc[e] + br[e];
        int e0 = 0; float s0 = lg[0];
        #pragma unroll
        for (int e = 1; e < NEXP; ++e) if (lg[e] > s0) { s0 = lg[e]; e0 = e; }
        int e1 = -1; float s1 = -1e30f;
        #pragma unroll
        for (int e = 0; e < NEXP; ++e) if (e != e0 && lg[e] > s1) { s1 = lg[e]; e1 = e; }
        float ex = expf(s1 - s0);
        float den = 1.f + ex;
        eids[t * 2] = e0; eids[t * 2 + 1] = e1;
        probs[t * 2] = 1.f / den; probs[t * 2 + 1] = ex / den;
    }
}

// ---------------- deterministic rank/capacity assignment (1 block, 1 wave) ----------------
__global__ void k_assign(const int* __restrict__ eids, int* __restrict__ tok_map,
                         int* __restrict__ dest) {
    __shared__ int cnt[64][NEXP];
    int l = threadIdx.x;                           // 64 threads
    for (int i = l; i < NEXP * CAP; i += 64) tok_map[i] = 0;   // default token 0 (weight 0)
    int c[NEXP];
    #pragma unroll
    for (int e = 0; e < NEXP; ++e) c[e] = 0;
    const int base = l * 256;                      // 64 * 256 = 16384 = NTOK*TOPK
    for (int i = 0; i < 256; ++i) {
        int ee = eids[base + i];
        #pragma unroll
        for (int e = 0; e < NEXP; ++e) c[e] += (ee == e);
    }
    #pragma unroll
    for (int e = 0; e < NEXP; ++e) cnt[l][e] = c[e];
    __syncthreads();
    if (l < NEXP) {                                // exclusive scan over 64 chunks
        int run = 0;
        for (int b = 0; b < 64; ++b) { int v = cnt[b][l]; cnt[b][l] = run; run += v; }
    }
    __syncthreads();
    int off[NEXP];
    #pragma unroll
    for (int e = 0; e < NEXP; ++e) off[e] = cnt[l][e];
    for (int i = 0; i < 256; ++i) {
        int d = base + i;
        int ee = eids[d];
        int r = -1;
        #pragma unroll
        for (int e = 0; e < NEXP; ++e) { bool m = (ee == e); if (m) r = off[e]; off[e] += m; }
        if (r < CAP) { tok_map[ee * CAP + r] = d >> 1; dest[d] = ee * CAP + r; }
        else dest[d] = -1;
    }
}

// ---------------- W [E][Kd][Nd] f32 -> WT [E][Nd][Kd] bf16 ----------------
__global__ void k_transpose(const float* __restrict__ src, ushort* __restrict__ dst,
                            int Kd, int Nd) {
    __shared__ float t[32][33];
    int e = blockIdx.z;
    int k0 = blockIdx.x * 32, n0 = blockIdx.y * 32;
    const float* s = src + (size_t)e * Kd * Nd;
    ushort* d = dst + (size_t)e * Kd * Nd;
    int tid = threadIdx.x;
    #pragma unroll
    for (int i = 0; i < 4; ++i) {
        int idx = i * 256 + tid; int kk = idx >> 5, nn = idx & 31;
        t[kk][nn] = s[(size_t)(k0 + kk) * Nd + n0 + nn];
    }
    __syncthreads();
    #pragma unroll
    for (int i = 0; i < 4; ++i) {
        int idx = i * 256 + tid; int nn = idx >> 5, kk = idx & 31;
        d[(size_t)(n0 + nn) * Kd + k0 + kk] = f2bf(t[kk][nn]);
    }
}

// ---------------- grouped bf16 MFMA GEMM: C = act(A . B^T + bias) ----------------
// A: rows of Kd bf16 (token rows via tmap if GATHER, else slot rows e*CAP+...)
// B: [E][Nd][Kd] bf16 (K-contiguous)   C: [E][CAP][Nd] bf16
#define LDA 40   // padded LDS row stride (bf16 elems); 80 B = 5*16 B, banks conflict-free
template<bool DOGELU, bool GATHER>
__global__ __launch_bounds__(256) void k_gemm(const ushort* __restrict__ A,
                                              const int* __restrict__ tmap,
                                              const ushort* __restrict__ B,
                                              const float* __restrict__ bias,
                                              ushort* __restrict__ C,
                                              int Kd, int Nd) {
    __shared__ ushort As[128 * LDA];
    __shared__ ushort Bs[128 * LDA];
    const int tid = threadIdx.x;
    const int lane = tid & 63;
    const int wave = tid >> 6;
    const int wr = wave >> 1, wc = wave & 1;
    const int e = blockIdx.z;
    const int bm0 = blockIdx.y * 128, bn0 = blockIdx.x * 128;

    const ushort* Be = B + (size_t)e * Nd * Kd;
    const int R  = tid >> 2;                 // 0..63, staging row pair (R, R+64)
    const int kc = (tid & 3) * 8;            // 0,8,16,24
    int ra0, ra1;
    if (GATHER) { ra0 = tmap[e * CAP + bm0 + R]; ra1 = tmap[e * CAP + bm0 + R + 64]; }
    else        { ra0 = e * CAP + bm0 + R;       ra1 = e * CAP + bm0 + R + 64; }
    const ushort* pa0 = A + (size_t)ra0 * Kd + kc;
    const ushort* pa1 = A + (size_t)ra1 * Kd + kc;
    const ushort* pb0 = Be + (size_t)(bn0 + R) * Kd + kc;
    const ushort* pb1 = Be + (size_t)(bn0 + R + 64) * Kd + kc;
    const int sa0 = R * LDA + kc, sa1 = (R + 64) * LDA + kc;

    const int fr = lane & 15, kg = (lane >> 4) * 8;
    f32x4 acc[4][4] = {};

    for (int k0 = 0; k0 < Kd; k0 += 32) {
        uint4 av0 = *(const uint4*)(pa0 + k0);
        uint4 av1 = *(const uint4*)(pa1 + k0);
        uint4 bv0 = *(const uint4*)(pb0 + k0);
        uint4 bv1 = *(const uint4*)(pb1 + k0);
        __syncthreads();
        *(uint4*)(As + sa0) = av0;
        *(uint4*)(As + sa1) = av1;
        *(uint4*)(Bs + sa0) = bv0;
        *(uint4*)(Bs + sa1) = bv1;
        __syncthreads();
        bf16x8 af[4], bfr[4];
        #pragma unroll
        for (int mi = 0; mi < 4; ++mi)
            af[mi] = *(const bf16x8*)(As + (wr * 64 + mi * 16 + fr) * LDA + kg);
        #pragma unroll
        for (int ni = 0; ni < 4; ++ni)
            bfr[ni] = *(const bf16x8*)(Bs + (wc * 64 + ni * 16 + fr) * LDA + kg);
        #pragma unroll
        for (int mi = 0; mi < 4; ++mi)
            #pragma unroll
            for (int ni = 0; ni < 4; ++ni)
                acc[mi][ni] = __builtin_amdgcn_mfma_f32_16x16x32_bf16(af[mi], bfr[ni],
                                                                      acc[mi][ni], 0, 0, 0);
    }

    const float* be = bias + e * Nd;
    ushort* Ce = C + (size_t)e * CAP * Nd;
    const int rl = (lane >> 4) * 4, cl = lane & 15;
    #pragma unroll
    for (int mi = 0; mi < 4; ++mi) {
        #pragma unroll
        for (int ni = 0; ni < 4; ++ni) {
            #pragma unroll
            for (int r = 0; r < 4; ++r) {
                int gr = bm0 + wr * 64 + mi * 16 + rl + r;
                int gc = bn0 + wc * 64 + ni * 16 + cl;
                float v = acc[mi][ni][r] + be[gc];
                if (DOGELU) v = 0.5f * v * (1.f + erff(v * 0.70710678118654752f));
                Ce[(size_t)gr * Nd + gc] = f2bf(v);
            }
        }
    }
}

// ---------------- deterministic combine: out[t] = sum_k p_k * Y[dest_k] ----------------
__global__ void k_combine(const ushort* __restrict__ Y, const int* __restrict__ dest,
                          const float* __restrict__ probs, float* __restrict__ out) {
    int t = blockIdx.x;
    int h0 = threadIdx.x * 8;
    int d0 = dest[t * 2], d1 = dest[t * 2 + 1];
    float p0 = d0 >= 0 ? probs[t * 2] : 0.f;
    float p1 = d1 >= 0 ? probs[t * 2 + 1] : 0.f;
    int r0 = d0 >= 0 ? d0 : 0, r1 = d1 >= 0 ? d1 : 0;
    uint4 a = *(const uint4*)(Y + (size_t)r0 * HDIM + h0);
    uint4 b = *(const uint4*)(Y + (size_t)r1 * HDIM + h0);
    float4 o0, o1;
    o0.x = p0 * bf2f(a.x & 0xffff) + p1 * bf2f(b.x & 0xffff);
    o0.y = p0 * bf2f(a.x >> 16)    + p1 * bf2f(b.x >> 16);
    o0.z = p0 * bf2f(a.y & 0xffff) + p1 * bf2f(b.y & 0xffff);
    o0.w = p0 * bf2f(a.y >> 16)    + p1 * bf2f(b.y >> 16);
    o1.x = p0 * bf2f(a.z & 0xffff) + p1 * bf2f(b.z & 0xffff);
    o1.y = p0 * bf2f(a.z >> 16)    + p1 * bf2f(b.z >> 16);
    o1.z = p0 * bf2f(a.w & 0xffff) + p1 * bf2f(b.w & 0xffff);
    o1.w = p0 * bf2f(a.w >> 16)    + p1 * bf2f(b.w >> 16);
    float* op = out + (size_t)t * HDIM + h0;
    *(float4*)op = o0;
    *(float4*)(op + 4) = o1;
}

extern "C" void kernel_launch(void* const* d_in, const int* in_sizes, int n_in,
                              void* d_out, int out_size, void* d_ws, size_t ws_size,
                              hipStream_t stream) {
    const float* tokens = (const float*)d_in[0];
    const float* Wr     = (const float*)d_in[1];
    const float* br     = (const float*)d_in[2];
    const float* W1     = (const float*)d_in[3];
    const float* b1     = (const float*)d_in[4];
    const float* W2     = (const float*)d_in[5];
    const float* b2     = (const float*)d_in[6];
    float* out = (float*)d_out;
    char* ws = (char*)d_ws;

    // workspace layout (peak ~249 MiB, phase-ordered reuse)
    int*    eids    = (int*)(ws);                  //  64 KB
    float*  probs   = (float*)(ws + 65536);        //  64 KB
    int*    tok_map = (int*)(ws + 131072);         //  40 KB
    int*    dest    = (int*)(ws + 172032);         //  64 KB
    size_t off = 1u << 20;
    ushort* TbY = (ushort*)(ws + off);             // tokens bf16 (33.5 MB) then Y bf16 (41.9 MB)
    off += 41943040;
    ushort* Hm  = (ushort*)(ws + off);             // gelu hidden bf16, 83.9 MB
    off += 83886080;
    ushort* WT  = (ushort*)(ws + off);             // W1T then W2T bf16, 134.2 MB
    (void)in_sizes; (void)n_in; (void)out_size; (void)ws_size;

    k_convert<<<dim3(NTOK * HDIM / 2048), 256, 0, stream>>>(tokens, TbY);
    k_router<<<dim3(NTOK / 4), 256, 0, stream>>>(tokens, Wr, br, eids, probs);
    k_assign<<<dim3(1), 64, 0, stream>>>(eids, tok_map, dest);
    k_transpose<<<dim3(HDIM / 32, FF / 32, NEXP), 256, 0, stream>>>(W1, WT, HDIM, FF);
    k_gemm<true, true><<<dim3(FF / 128, CAP / 128, NEXP), 256, 0, stream>>>(
        TbY, tok_map, WT, b1, Hm, HDIM, FF);
    k_transpose<<<dim3(FF / 32, HDIM / 32, NEXP), 256, 0, stream>>>(W2, WT, FF, HDIM);
    k_gemm<false, false><<<dim3(HDIM / 128, CAP / 128, NEXP), 256, 0, stream>>>(
        Hm, nullptr, WT, b2, TbY, FF, HDIM);
    k_combine<<<dim3(NTOK), 256, 0, stream>>>(TbY, dest, probs, out);
}

// Round 2
// 818.703 us; speedup vs baseline: 1.0578x; 1.0578x over previous
//
#include <hip/hip_runtime.h>
#include <hip/hip_bf16.h>
#include <math.h>

// Problem constants (reference: N=8192, H=2048, E=8, K=2, CF=1.25)
#define NTOK 8192
#define HDIM 2048
#define NEXP 8
#define TOPK 2
#define CAP  1280            // ceil(1.25 * 8192 / 8)
#define FF   4096            // 2*H
#define BK   32              // GEMM K-step

typedef float  f32x4  __attribute__((ext_vector_type(4)));
typedef __bf16 bf16x8 __attribute__((ext_vector_type(8)));

typedef __attribute__((address_space(1))) const unsigned int gas_u32;
typedef __attribute__((address_space(3))) unsigned int las_u32;

__device__ __forceinline__ void gload16(const void* g, void* l) {
    // async global -> LDS, 16 B per lane; LDS dest = wave-uniform base + lane*16
    __builtin_amdgcn_global_load_lds((gas_u32*)g, (las_u32*)l, 16, 0, 0);
}

__device__ __forceinline__ ushort f2bf(float f) {
    union { float f; unsigned u; } c; c.f = f;
    unsigned u = c.u;
    unsigned r = (u + 0x7FFFu + ((u >> 16) & 1u)) >> 16;   // RNE
    return (ushort)r;
}
__device__ __forceinline__ float bf2f(ushort h) {
    union { unsigned u; float f; } c; c.u = ((unsigned)h) << 16;
    return c.f;
}

// ---------------- tokens f32 -> bf16 ----------------
__global__ void k_convert(const float* __restrict__ src, ushort* __restrict__ dst) {
    int i = (blockIdx.x * 256 + threadIdx.x) * 8;
    float4 a = *(const float4*)(src + i);
    float4 b = *(const float4*)(src + i + 4);
    uint4 o;
    o.x = (unsigned)f2bf(a.x) | ((unsigned)f2bf(a.y) << 16);
    o.y = (unsigned)f2bf(a.z) | ((unsigned)f2bf(a.w) << 16);
    o.z = (unsigned)f2bf(b.x) | ((unsigned)f2bf(b.y) << 16);
    o.w = (unsigned)f2bf(b.z) | ((unsigned)f2bf(b.w) << 16);
    *(uint4*)(dst + i) = o;
}

// ---------------- router: logits (f64 accum), top-2, softmax ----------------
__global__ void k_router(const float* __restrict__ tokens, const float* __restrict__ Wr,
                         const float* __restrict__ br, int* __restrict__ eids,
                         float* __restrict__ probs) {
    int wave = threadIdx.x >> 6, lane = threadIdx.x & 63;
    int t = blockIdx.x * 4 + wave;
    const float* tp = tokens + (size_t)t * HDIM;
    double acc[NEXP];
    #pragma unroll
    for (int e = 0; e < NEXP; ++e) acc[e] = 0.0;
    for (int j = 0; j < HDIM / 64; ++j) {
        float x = tp[j * 64 + lane];
        #pragma unroll
        for (int e = 0; e < NEXP; ++e)
            acc[e] += (double)x * (double)Wr[e * HDIM + j * 64 + lane];
    }
    #pragma unroll
    for (int e = 0; e < NEXP; ++e) {
        #pragma unroll
        for (int off = 32; off; off >>= 1) acc[e] += __shfl_xor(acc[e], off, 64);
    }
    if (lane == 0) {
        float lg[NEXP];
        #pragma unroll
        for (int e = 0; e < NEXP; ++e) lg[e] = (float)acc[e] + br[e];
        int e0 = 0; float s0 = lg[0];
        #pragma unroll
        for (int e = 1; e < NEXP; ++e) if (lg[e] > s0) { s0 = lg[e]; e0 = e; }
        int e1 = -1; float s1 = -1e30f;
        #pragma unroll
        for (int e = 0; e < NEXP; ++e) if (e != e0 && lg[e] > s1) { s1 = lg[e]; e1 = e; }
        float ex = expf(s1 - s0);
        float den = 1.f + ex;
        eids[t * 2] = e0; eids[t * 2 + 1] = e1;
        probs[t * 2] = 1.f / den; probs[t * 2 + 1] = ex / den;
    }
}

// ---------------- deterministic rank/capacity assignment (1 block, 1 wave) ----------------
__global__ void k_assign(const int* __restrict__ eids, int* __restrict__ tok_map,
                         int* __restrict__ dest) {
    __shared__ int cnt[64][NEXP];
    int l = threadIdx.x;                           // 64 threads
    for (int i = l; i < NEXP * CAP; i += 64) tok_map[i] = 0;   // default token 0 (weight 0)
    int c[NEXP];
    #pragma unroll
    for (int e = 0; e < NEXP; ++e) c[e] = 0;
    const int base = l * 256;                      // 64 * 256 = 16384 = NTOK*TOPK
    for (int i = 0; i < 256; ++i) {
        int ee = eids[base + i];
        #pragma unroll
        for (int e = 0; e < NEXP; ++e) c[e] += (ee == e);
    }
    #pragma unroll
    for (int e = 0; e < NEXP; ++e) cnt[l][e] = c[e];
    __syncthreads();
    if (l < NEXP) {                                // exclusive scan over 64 chunks
        int run = 0;
        for (int b = 0; b < 64; ++b) { int v = cnt[b][l]; cnt[b][l] = run; run += v; }
    }
    __syncthreads();
    int off[NEXP];
    #pragma unroll
    for (int e = 0; e < NEXP; ++e) off[e] = cnt[l][e];
    for (int i = 0; i < 256; ++i) {
        int d = base + i;
        int ee = eids[d];
        int r = -1;
        #pragma unroll
        for (int e = 0; e < NEXP; ++e) { bool m = (ee == e); if (m) r = off[e]; off[e] += m; }
        if (r < CAP) { tok_map[ee * CAP + r] = d >> 1; dest[d] = ee * CAP + r; }
        else dest[d] = -1;
    }
}

// ---------------- W [E][Kd][Nd] f32 -> WT [E][Nd][Kd] bf16, 64x64 tiles ----------------
__global__ __launch_bounds__(256) void k_transpose(const float* __restrict__ src,
                                                   ushort* __restrict__ dst,
                                                   int Kd, int Nd) {
    __shared__ float tl[64][65];
    int e = blockIdx.z;
    int k0 = blockIdx.x * 64, n0 = blockIdx.y * 64;
    const float* s = src + (size_t)e * Kd * Nd;
    ushort* d = dst + (size_t)e * Kd * Nd;
    int tid = threadIdx.x;
    #pragma unroll
    for (int i = 0; i < 4; ++i) {
        int flat = (i * 256 + tid) * 4;            // 0..4092, nn multiple of 4
        int kk = flat >> 6, nn = flat & 63;
        float4 v = *(const float4*)(s + (size_t)(k0 + kk) * Nd + n0 + nn);
        tl[kk][nn] = v.x; tl[kk][nn + 1] = v.y; tl[kk][nn + 2] = v.z; tl[kk][nn + 3] = v.w;
    }
    __syncthreads();
    #pragma unroll
    for (int g = 0; g < 4; ++g) {
        int flat = g * 1024 + tid * 4;             // kk multiple of 4
        int nn = flat >> 6, kk = flat & 63;
        uint2 o;
        o.x = (unsigned)f2bf(tl[kk][nn])     | ((unsigned)f2bf(tl[kk + 1][nn]) << 16);
        o.y = (unsigned)f2bf(tl[kk + 2][nn]) | ((unsigned)f2bf(tl[kk + 3][nn]) << 16);
        *(uint2*)(d + (size_t)(n0 + nn) * Kd + k0 + kk) = o;
    }
}

// ---------------- grouped bf16 MFMA GEMM (m97 structure): C = act(A . B^T + bias) ----------------
// A: rows of Kd bf16 (token rows via tmap if GATHER, else slot rows e*CAP+...)
// B: [E][Nd][Kd] bf16 (K-contiguous)   C: [E][CAP][Nd] bf16
// Linear LDS [128][BK], staged via global_load_lds dwordx4 (wave-uniform dest + lane*16).
template<bool DOGELU, bool GATHER>
__global__ __launch_bounds__(256) void k_gemm(const ushort* __restrict__ A,
                                              const int* __restrict__ tmap,
                                              const ushort* __restrict__ B,
                                              const float* __restrict__ bias,
                                              ushort* __restrict__ C,
                                              int Kd, int Nd) {
    __shared__ ushort As[128 * BK];
    __shared__ ushort Bs[128 * BK];
    const int tid = threadIdx.x;
    const int lane = tid & 63;
    const int wave = tid >> 6;
    const int wr = wave >> 1, wc = wave & 1;
    const int e = blockIdx.z;
    const int bm0 = blockIdx.y * 128, bn0 = blockIdx.x * 128;

    const ushort* Be = B + (size_t)e * Nd * Kd;
    // staging map: thread tid -> row R = tid>>2 (and R+64), k-chunk kc = (tid&3)*8 elems.
    // LDS byte offset = R*64 + (tid&3)*16 = tid*16  (linear; wave base = wave*1024)
    const int R  = tid >> 2;
    const int kc = (tid & 3) * 8;
    int ra0, ra1;
    if (GATHER) { ra0 = tmap[e * CAP + bm0 + R]; ra1 = tmap[e * CAP + bm0 + R + 64]; }
    else        { ra0 = e * CAP + bm0 + R;       ra1 = e * CAP + bm0 + R + 64; }
    const ushort* pa0 = A + (size_t)ra0 * Kd + kc;
    const ushort* pa1 = A + (size_t)ra1 * Kd + kc;
    const ushort* pb0 = Be + (size_t)(bn0 + R) * Kd + kc;
    const ushort* pb1 = Be + (size_t)(bn0 + R + 64) * Kd + kc;
    char* lA0 = (char*)As + wave * 1024;
    char* lA1 = (char*)As + 4096 + wave * 1024;
    char* lB0 = (char*)Bs + wave * 1024;
    char* lB1 = (char*)Bs + 4096 + wave * 1024;

    const int fr = lane & 15, kg = (lane >> 4) * 8;
    f32x4 acc[4][4] = {};

    for (int k0 = 0; k0 < Kd; k0 += BK) {
        __syncthreads();                       // prev tile fully consumed
        gload16(pa0 + k0, lA0);
        gload16(pa1 + k0, lA1);
        gload16(pb0 + k0, lB0);
        gload16(pb1 + k0, lB1);
        __syncthreads();                       // vmcnt(0) drain + barrier: tile ready
        bf16x8 af[4], bfr[4];
        #pragma unroll
        for (int mi = 0; mi < 4; ++mi)
            af[mi] = *(const bf16x8*)(As + (wr * 64 + mi * 16 + fr) * BK + kg);
        #pragma unroll
        for (int ni = 0; ni < 4; ++ni)
            bfr[ni] = *(const bf16x8*)(Bs + (wc * 64 + ni * 16 + fr) * BK + kg);
        #pragma unroll
        for (int mi = 0; mi < 4; ++mi)
            #pragma unroll
            for (int ni = 0; ni < 4; ++ni)
                acc[mi][ni] = __builtin_amdgcn_mfma_f32_16x16x32_bf16(af[mi], bfr[ni],
                                                                      acc[mi][ni], 0, 0, 0);
    }

    const float* be = bias + e * Nd;
    ushort* Ce = C + (size_t)e * CAP * Nd;
    const int rl = (lane >> 4) * 4, cl = lane & 15;
    #pragma unroll
    for (int mi = 0; mi < 4; ++mi) {
        #pragma unroll
        for (int ni = 0; ni < 4; ++ni) {
            #pragma unroll
            for (int r = 0; r < 4; ++r) {
                int gr = bm0 + wr * 64 + mi * 16 + rl + r;
                int gc = bn0 + wc * 64 + ni * 16 + cl;
                float v = acc[mi][ni][r] + be[gc];
                if (DOGELU) v = 0.5f * v * (1.f + erff(v * 0.70710678118654752f));
                Ce[(size_t)gr * Nd + gc] = f2bf(v);
            }
        }
    }
}

// ---------------- deterministic combine: out[t] = sum_k p_k * Y[dest_k] ----------------
__global__ void k_combine(const ushort* __restrict__ Y, const int* __restrict__ dest,
                          const float* __restrict__ probs, float* __restrict__ out) {
    int t = blockIdx.x;
    int h0 = threadIdx.x * 8;
    int d0 = dest[t * 2], d1 = dest[t * 2 + 1];
    float p0 = d0 >= 0 ? probs[t * 2] : 0.f;
    float p1 = d1 >= 0 ? probs[t * 2 + 1] : 0.f;
    int r0 = d0 >= 0 ? d0 : 0, r1 = d1 >= 0 ? d1 : 0;
    uint4 a = *(const uint4*)(Y + (size_t)r0 * HDIM + h0);
    uint4 b = *(const uint4*)(Y + (size_t)r1 * HDIM + h0);
    float4 o0, o1;
    o0.x = p0 * bf2f(a.x & 0xffff) + p1 * bf2f(b.x & 0xffff);
    o0.y = p0 * bf2f(a.x >> 16)    + p1 * bf2f(b.x >> 16);
    o0.z = p0 * bf2f(a.y & 0xffff) + p1 * bf2f(b.y & 0xffff);
    o0.w = p0 * bf2f(a.y >> 16)    + p1 * bf2f(b.y >> 16);
    o1.x = p0 * bf2f(a.z & 0xffff) + p1 * bf2f(b.z & 0xffff);
    o1.y = p0 * bf2f(a.z >> 16)    + p1 * bf2f(b.z >> 16);
    o1.z = p0 * bf2f(a.w & 0xffff) + p1 * bf2f(b.w & 0xffff);
    o1.w = p0 * bf2f(a.w >> 16)    + p1 * bf2f(b.w >> 16);
    float* op = out + (size_t)t * HDIM + h0;
    *(float4*)op = o0;
    *(float4*)(op + 4) = o1;
}

extern "C" void kernel_launch(void* const* d_in, const int* in_sizes, int n_in,
                              void* d_out, int out_size, void* d_ws, size_t ws_size,
                              hipStream_t stream) {
    const float* tokens = (const float*)d_in[0];
    const float* Wr     = (const float*)d_in[1];
    const float* br     = (const float*)d_in[2];
    const float* W1     = (const float*)d_in[3];
    const float* b1     = (const float*)d_in[4];
    const float* W2     = (const float*)d_in[5];
    const float* b2     = (const float*)d_in[6];
    float* out = (float*)d_out;
    char* ws = (char*)d_ws;

    // workspace layout (peak ~249 MiB, phase-ordered reuse)
    int*    eids    = (int*)(ws);                  //  64 KB
    float*  probs   = (float*)(ws + 65536);        //  64 KB
    int*    tok_map = (int*)(ws + 131072);         //  40 KB
    int*    dest    = (int*)(ws + 172032);         //  64 KB
    size_t off = 1u << 20;
    ushort* TbY = (ushort*)(ws + off);             // tokens bf16 (33.5 MB) then Y bf16 (41.9 MB)
    off += 41943040;
    ushort* Hm  = (ushort*)(ws + off);             // gelu hidden bf16, 83.9 MB
    off += 83886080;
    ushort* WT  = (ushort*)(ws + off);             // W1T then W2T bf16, 134.2 MB
    (void)in_sizes; (void)n_in; (void)out_size; (void)ws_size;

    k_convert<<<dim3(NTOK * HDIM / 2048), 256, 0, stream>>>(tokens, TbY);
    k_router<<<dim3(NTOK / 4), 256, 0, stream>>>(tokens, Wr, br, eids, probs);
    k_assign<<<dim3(1), 64, 0, stream>>>(eids, tok_map, dest);
    k_transpose<<<dim3(HDIM / 64, FF / 64, NEXP), 256, 0, stream>>>(W1, WT, HDIM, FF);
    k_gemm<true, true><<<dim3(FF / 128, CAP / 128, NEXP), 256, 0, stream>>>(
        TbY, tok_map, WT, b1, Hm, HDIM, FF);
    k_transpose<<<dim3(FF / 64, HDIM / 64, NEXP), 256, 0, stream>>>(W2, WT, FF, HDIM);
    k_gemm<false, false><<<dim3(HDIM / 128, CAP / 128, NEXP), 256, 0, stream>>>(
        Hm, nullptr, WT, b2, TbY, FF, HDIM);
    k_combine<<<dim3(NTOK), 256, 0, stream>>>(TbY, dest, probs, out);
}

// Round 3
// 757.491 us; speedup vs baseline: 1.1432x; 1.0808x over previous
//
#include <hip/hip_runtime.h>
#include <hip/hip_bf16.h>
#include <math.h>

// Problem constants (reference: N=8192, H=2048, E=8, K=2, CF=1.25)
#define NTOK 8192
#define HDIM 2048
#define NEXP 8
#define TOPK 2
#define CAP  1280            // ceil(1.25 * 8192 / 8)
#define FF   4096            // 2*H

typedef float  f32x4  __attribute__((ext_vector_type(4)));
typedef __bf16 bf16x8 __attribute__((ext_vector_type(8)));

typedef __attribute__((address_space(1))) const unsigned int gas_u32;
typedef __attribute__((address_space(3))) unsigned int las_u32;

__device__ __forceinline__ void gload16(const void* g, void* l) {
    // async global -> LDS, 16 B per lane; LDS dest = wave-uniform base + lane*16
    __builtin_amdgcn_global_load_lds((gas_u32*)g, (las_u32*)l, 16, 0, 0);
}

__device__ __forceinline__ ushort f2bf(float f) {
    union { float f; unsigned u; } c; c.f = f;
    unsigned u = c.u;
    unsigned r = (u + 0x7FFFu + ((u >> 16) & 1u)) >> 16;   // RNE
    return (ushort)r;
}
__device__ __forceinline__ float bf2f(ushort h) {
    union { unsigned u; float f; } c; c.u = ((unsigned)h) << 16;
    return c.f;
}

// ---------------- tokens f32 -> bf16 ----------------
__global__ void k_convert(const float* __restrict__ src, ushort* __restrict__ dst) {
    int i = (blockIdx.x * 256 + threadIdx.x) * 8;
    float4 a = *(const float4*)(src + i);
    float4 b = *(const float4*)(src + i + 4);
    uint4 o;
    o.x = (unsigned)f2bf(a.x) | ((unsigned)f2bf(a.y) << 16);
    o.y = (unsigned)f2bf(a.z) | ((unsigned)f2bf(a.w) << 16);
    o.z = (unsigned)f2bf(b.x) | ((unsigned)f2bf(b.y) << 16);
    o.w = (unsigned)f2bf(b.z) | ((unsigned)f2bf(b.w) << 16);
    *(uint4*)(dst + i) = o;
}

// ---------------- router: logits (f64 accum), top-2, softmax ----------------
__global__ void k_router(const float* __restrict__ tokens, const float* __restrict__ Wr,
                         const float* __restrict__ br, int* __restrict__ eids,
                         float* __restrict__ probs) {
    int wave = threadIdx.x >> 6, lane = threadIdx.x & 63;
    int t = blockIdx.x * 4 + wave;
    const float* tp = tokens + (size_t)t * HDIM;
    double acc[NEXP];
    #pragma unroll
    for (int e = 0; e < NEXP; ++e) acc[e] = 0.0;
    for (int j = 0; j < HDIM / 64; ++j) {
        float x = tp[j * 64 + lane];
        #pragma unroll
        for (int e = 0; e < NEXP; ++e)
            acc[e] += (double)x * (double)Wr[e * HDIM + j * 64 + lane];
    }
    #pragma unroll
    for (int e = 0; e < NEXP; ++e) {
        #pragma unroll
        for (int off = 32; off; off >>= 1) acc[e] += __shfl_xor(acc[e], off, 64);
    }
    if (lane == 0) {
        float lg[NEXP];
        #pragma unroll
        for (int e = 0; e < NEXP; ++e) lg[e] = (float)acc[e] + br[e];
        int e0 = 0; float s0 = lg[0];
        #pragma unroll
        for (int e = 1; e < NEXP; ++e) if (lg[e] > s0) { s0 = lg[e]; e0 = e; }
        int e1 = -1; float s1 = -1e30f;
        #pragma unroll
        for (int e = 0; e < NEXP; ++e) if (e != e0 && lg[e] > s1) { s1 = lg[e]; e1 = e; }
        float ex = expf(s1 - s0);
        float den = 1.f + ex;
        eids[t * 2] = e0; eids[t * 2 + 1] = e1;
        probs[t * 2] = 1.f / den; probs[t * 2 + 1] = ex / den;
    }
}

// ---------------- deterministic rank/capacity assignment (1 block, 1 wave) ----------------
__global__ void k_assign(const int* __restrict__ eids, int* __restrict__ tok_map,
                         int* __restrict__ dest) {
    __shared__ int cnt[64][NEXP];
    int l = threadIdx.x;                           // 64 threads
    for (int i = l; i < NEXP * CAP; i += 64) tok_map[i] = 0;   // default token 0 (weight 0)
    int c[NEXP];
    #pragma unroll
    for (int e = 0; e < NEXP; ++e) c[e] = 0;
    const int base = l * 256;                      // 64 * 256 = 16384 = NTOK*TOPK
    for (int i = 0; i < 256; ++i) {
        int ee = eids[base + i];
        #pragma unroll
        for (int e = 0; e < NEXP; ++e) c[e] += (ee == e);
    }
    #pragma unroll
    for (int e = 0; e < NEXP; ++e) cnt[l][e] = c[e];
    __syncthreads();
    if (l < NEXP) {                                // exclusive scan over 64 chunks
        int run = 0;
        for (int b = 0; b < 64; ++b) { int v = cnt[b][l]; cnt[b][l] = run; run += v; }
    }
    __syncthreads();
    int off[NEXP];
    #pragma unroll
    for (int e = 0; e < NEXP; ++e) off[e] = cnt[l][e];
    for (int i = 0; i < 256; ++i) {
        int d = base + i;
        int ee = eids[d];
        int r = -1;
        #pragma unroll
        for (int e = 0; e < NEXP; ++e) { bool m = (ee == e); if (m) r = off[e]; off[e] += m; }
        if (r < CAP) { tok_map[ee * CAP + r] = d >> 1; dest[d] = ee * CAP + r; }
        else dest[d] = -1;
    }
}

// ---------------- W [E][Kd][Nd] f32 -> WT [E][Nd][Kd] bf16, 64x64 tiles ----------------
__global__ __launch_bounds__(256) void k_transpose(const float* __restrict__ src,
                                                   ushort* __restrict__ dst,
                                                   int Kd, int Nd) {
    __shared__ float tl[64][65];
    int e = blockIdx.z;
    int k0 = blockIdx.x * 64, n0 = blockIdx.y * 64;
    const float* s = src + (size_t)e * Kd * Nd;
    ushort* d = dst + (size_t)e * Kd * Nd;
    int tid = threadIdx.x;
    #pragma unroll
    for (int i = 0; i < 4; ++i) {
        int flat = (i * 256 + tid) * 4;            // 0..4092, nn multiple of 4
        int kk = flat >> 6, nn = flat & 63;
        float4 v = *(const float4*)(s + (size_t)(k0 + kk) * Nd + n0 + nn);
        tl[kk][nn] = v.x; tl[kk][nn + 1] = v.y; tl[kk][nn + 2] = v.z; tl[kk][nn + 3] = v.w;
    }
    __syncthreads();
    #pragma unroll
    for (int g = 0; g < 4; ++g) {
        int flat = g * 1024 + tid * 4;             // kk multiple of 4
        int nn = flat >> 6, kk = flat & 63;
        uint2 o;
        o.x = (unsigned)f2bf(tl[kk][nn])     | ((unsigned)f2bf(tl[kk + 1][nn]) << 16);
        o.y = (unsigned)f2bf(tl[kk + 2][nn]) | ((unsigned)f2bf(tl[kk + 3][nn]) << 16);
        *(uint2*)(d + (size_t)(n0 + nn) * Kd + k0 + kk) = o;
    }
}

// ---------------- grouped bf16 MFMA GEMM, 256x256 8-phase (m201 structure) ----------------
// C = act(A . B^T + bias). A: rows of Kd bf16 (via tmap if GATHER, else slot rows).
// B: [E][Nd][Kd] bf16 (K-contiguous). C: [E][CAP][Nd] bf16.
// 8 waves (2M x 4N), per-wave out 128x64. BK=64. LDS 128 KiB:
//   A: buf*32768 + half*16384  (even K-tile -> buf0, odd -> buf1; static)
//   B: 65536 + same. Each half = [128 rows][64 k] bf16, row stride 128 B.
// XOR-swizzle (G4): LDS byte-in-row ^= (row&7)<<4, realized as linear LDS dest +
// inverse-swizzled GLOBAL source (involution) + swizzled ds_read address.
// Staging clusters at phases 1/3/5/7 (one tile, 4 gloads); vmcnt(4) at phases 4,8 only.
#define BAR()   asm volatile("s_barrier" ::: "memory")
#define VMC4()  asm volatile("s_waitcnt vmcnt(4)" ::: "memory")

template<bool DOGELU, bool GATHER>
__global__ __launch_bounds__(512, 2) void k_gemm(const ushort* __restrict__ A,
                                                 const int* __restrict__ tmap,
                                                 const ushort* __restrict__ B,
                                                 const float* __restrict__ bias,
                                                 ushort* __restrict__ C,
                                                 int Kd, int Nd) {
    __shared__ char lds[131072];
    const int tid  = threadIdx.x;
    const int lane = tid & 63;
    const int wave = tid >> 6;                    // 0..7
    const int wr = wave >> 2, wc = wave & 3;      // 2 x 4 wave grid
    const int e = blockIdx.z;
    const int bm0 = blockIdx.y * 256, bn0 = blockIdx.x * 256;

    // ---------- staging setup ----------
    const int srow = tid >> 3;                    // 0..63 within a 64-row group
    const int swzc = (tid ^ (tid >> 3)) & 7;      // inverse-swizzled 16B chunk (involution)
    const ushort* Be = B + (size_t)e * (size_t)Nd * Kd;
    const ushort* pa[4]; const ushort* pb[4];
    #pragma unroll
    for (int h = 0; h < 2; ++h)
        #pragma unroll
        for (int j = 0; j < 2; ++j) {
            int mrow = bm0 + h * 128 + j * 64 + srow;
            int arow = GATHER ? tmap[e * CAP + mrow] : (e * CAP + mrow);
            pa[h * 2 + j] = A  + (size_t)arow * Kd + swzc * 8;
            pb[h * 2 + j] = Be + (size_t)(bn0 + h * 128 + j * 64 + srow) * Kd + swzc * 8;
        }
    const int ldsW = wave * 1024;                 // wave-uniform lane block

    // ---------- compute-side fragment addressing ----------
    const int fr = lane & 15, kq = lane >> 4;     // frag row/col, k-quarter
    const int x0 = ((kq ^ (fr & 7)) * 16);        // swizzled 16B chunk byte, ks=0
    const int sA = wr * 16384 + fr * 128;                              // A: half = wr
    const int sB = 65536 + (wc >> 1) * 16384 + ((wc & 1) * 64 + fr) * 128; // B: half = wc>>1

    f32x4  acc[8][4] = {};
    bf16x8 bfr[4][2];                             // all 4 B n-frags x 2 k-slices live

    auto STAGE_A = [&](int b, int kt) {
        #pragma unroll
        for (int hj = 0; hj < 4; ++hj)
            gload16(pa[hj] + (size_t)kt * 64,
                    lds + b * 32768 + (hj >> 1) * 16384 + (hj & 1) * 8192 + ldsW);
    };
    auto STAGE_B = [&](int b, int kt) {
        #pragma unroll
        for (int hj = 0; hj < 4; ++hj)
            gload16(pb[hj] + (size_t)kt * 64,
                    lds + 65536 + b * 32768 + (hj >> 1) * 16384 + (hj & 1) * 8192 + ldsW);
    };
    auto LDA_ = [&](bf16x8 (&af)[4][2], int b, int mh) {
        #pragma unroll
        for (int m = 0; m < 4; ++m)
            #pragma unroll
            for (int ks = 0; ks < 2; ++ks)
                af[m][ks] = *(const bf16x8*)(lds + b * 32768 + sA + (mh * 4 + m) * 2048
                                             + (x0 ^ (ks << 6)));
    };
    auto LDB2 = [&](int b, int nh) {
        #pragma unroll
        for (int n = 0; n < 2; ++n)
            #pragma unroll
            for (int ks = 0; ks < 2; ++ks)
                bfr[nh * 2 + n][ks] = *(const bf16x8*)(lds + b * 32768 + sB
                                                       + (nh * 2 + n) * 2048 + (x0 ^ (ks << 6)));
    };
    auto MMA = [&](bf16x8 (&af)[4][2], int mh, int nh) {
        __builtin_amdgcn_s_setprio(1);
        #pragma unroll
        for (int m = 0; m < 4; ++m)
            #pragma unroll
            for (int n = 0; n < 2; ++n)
                #pragma unroll
                for (int ks = 0; ks < 2; ++ks)
                    acc[mh * 4 + m][nh * 2 + n] = __builtin_amdgcn_mfma_f32_16x16x32_bf16(
                        af[m][ks], bfr[nh * 2 + n][ks], acc[mh * 4 + m][nh * 2 + n], 0, 0, 0);
        __builtin_amdgcn_s_setprio(0);
    };

    const int NT  = Kd >> 6;                      // K-tiles (even for both GEMMs)
    const int nt2 = NT >> 1;                      // iterations (2 K-tiles each)

    // ---------- prologue: A(0),B(0) -> buf0; B(1) -> buf1 ----------
    STAGE_A(0, 0); STAGE_B(0, 0); STAGE_B(1, 1);
    VMC4();                                        // A(0),B(0) landed; B(1) in flight
    BAR();

    for (int it = 0; it < nt2; ++it) {
        const int kt1  = 2 * it + 1;
        const int ktN  = min(2 * it + 2, NT - 1);  // next even tile (clamped on last iter)
        const int ktN1 = min(2 * it + 3, NT - 1);  // next odd tile
        bf16x8 af[4][2];
        // ph1: tile kt0(buf0) quadrant (0,0); stage A(kt1)->buf1
        LDA_(af, 0, 0); LDB2(0, 0);
        STAGE_A(1, kt1);
        BAR(); MMA(af, 0, 0); BAR();
        // ph2: quadrant (0,1)
        LDB2(0, 1);
        BAR(); MMA(af, 0, 1); BAR();
        // ph3: quadrant (1,0); stage B(ktN)->buf0 (B-buf0 consumed at ph2)
        LDA_(af, 0, 1);
        STAGE_B(0, ktN);
        BAR(); MMA(af, 1, 0); BAR();
        // ph4: quadrant (1,1); confirm A(kt1),B(kt1) landed for ph5-8
        VMC4();
        BAR(); MMA(af, 1, 1); BAR();
        // ph5: tile kt1(buf1) quadrant (0,0); stage A(ktN)->buf0 (A-buf0 consumed at ph3)
        LDA_(af, 1, 0); LDB2(1, 0);
        STAGE_A(0, ktN);
        BAR(); MMA(af, 0, 0); BAR();
        // ph6: quadrant (0,1)
        LDB2(1, 1);
        BAR(); MMA(af, 0, 1); BAR();
        // ph7: quadrant (1,0); stage B(ktN1)->buf1 (B-buf1 consumed at ph6)
        LDA_(af, 1, 1);
        STAGE_B(1, ktN1);
        BAR(); MMA(af, 1, 0); BAR();
        // ph8: quadrant (1,1); confirm B(ktN),A(ktN) landed for next ph1-4
        VMC4();
        BAR(); MMA(af, 1, 1); BAR();
    }

    // ---------- epilogue ----------
    const float* be = bias + e * Nd;
    ushort* Ce = C + (size_t)e * CAP * Nd;
    const int rl = (lane >> 4) * 4, cl = lane & 15;
    #pragma unroll
    for (int ni = 0; ni < 4; ++ni) {
        int gc = bn0 + wc * 64 + ni * 16 + cl;
        float bv = be[gc];
        #pragma unroll
        for (int mi = 0; mi < 8; ++mi) {
            #pragma unroll
            for (int r = 0; r < 4; ++r) {
                int gr = bm0 + wr * 128 + mi * 16 + rl + r;
                float v = acc[mi][ni][r] + bv;
                if (DOGELU) v = 0.5f * v * (1.f + erff(v * 0.70710678118654752f));
                Ce[(size_t)gr * Nd + gc] = f2bf(v);
            }
        }
    }
}

// ---------------- deterministic combine: out[t] = sum_k p_k * Y[dest_k] ----------------
__global__ void k_combine(const ushort* __restrict__ Y, const int* __restrict__ dest,
                          const float* __restrict__ probs, float* __restrict__ out) {
    int t = blockIdx.x;
    int h0 = threadIdx.x * 8;
    int d0 = dest[t * 2], d1 = dest[t * 2 + 1];
    float p0 = d0 >= 0 ? probs[t * 2] : 0.f;
    float p1 = d1 >= 0 ? probs[t * 2 + 1] : 0.f;
    int r0 = d0 >= 0 ? d0 : 0, r1 = d1 >= 0 ? d1 : 0;
    uint4 a = *(const uint4*)(Y + (size_t)r0 * HDIM + h0);
    uint4 b = *(const uint4*)(Y + (size_t)r1 * HDIM + h0);
    float4 o0, o1;
    o0.x = p0 * bf2f(a.x & 0xffff) + p1 * bf2f(b.x & 0xffff);
    o0.y = p0 * bf2f(a.x >> 16)    + p1 * bf2f(b.x >> 16);
    o0.z = p0 * bf2f(a.y & 0xffff) + p1 * bf2f(b.y & 0xffff);
    o0.w = p0 * bf2f(a.y >> 16)    + p1 * bf2f(b.y >> 16);
    o1.x = p0 * bf2f(a.z & 0xffff) + p1 * bf2f(b.z & 0xffff);
    o1.y = p0 * bf2f(a.z >> 16)    + p1 * bf2f(b.z >> 16);
    o1.z = p0 * bf2f(a.w & 0xffff) + p1 * bf2f(b.w & 0xffff);
    o1.w = p0 * bf2f(a.w >> 16)    + p1 * bf2f(b.w >> 16);
    float* op = out + (size_t)t * HDIM + h0;
    *(float4*)op = o0;
    *(float4*)(op + 4) = o1;
}

extern "C" void kernel_launch(void* const* d_in, const int* in_sizes, int n_in,
                              void* d_out, int out_size, void* d_ws, size_t ws_size,
                              hipStream_t stream) {
    const float* tokens = (const float*)d_in[0];
    const float* Wr     = (const float*)d_in[1];
    const float* br     = (const float*)d_in[2];
    const float* W1     = (const float*)d_in[3];
    const float* b1     = (const float*)d_in[4];
    const float* W2     = (const float*)d_in[5];
    const float* b2     = (const float*)d_in[6];
    float* out = (float*)d_out;
    char* ws = (char*)d_ws;

    // workspace layout (peak ~249 MiB, phase-ordered reuse)
    int*    eids    = (int*)(ws);                  //  64 KB
    float*  probs   = (float*)(ws + 65536);        //  64 KB
    int*    tok_map = (int*)(ws + 131072);         //  40 KB
    int*    dest    = (int*)(ws + 172032);         //  64 KB
    size_t off = 1u << 20;
    ushort* TbY = (ushort*)(ws + off);             // tokens bf16 (33.5 MB) then Y bf16 (41.9 MB)
    off += 41943040;
    ushort* Hm  = (ushort*)(ws + off);             // gelu hidden bf16, 83.9 MB
    off += 83886080;
    ushort* WT  = (ushort*)(ws + off);             // W1T then W2T bf16, 134.2 MB
    (void)in_sizes; (void)n_in; (void)out_size; (void)ws_size;

    k_convert<<<dim3(NTOK * HDIM / 2048), 256, 0, stream>>>(tokens, TbY);
    k_router<<<dim3(NTOK / 4), 256, 0, stream>>>(tokens, Wr, br, eids, probs);
    k_assign<<<dim3(1), 64, 0, stream>>>(eids, tok_map, dest);
    k_transpose<<<dim3(HDIM / 64, FF / 64, NEXP), 256, 0, stream>>>(W1, WT, HDIM, FF);
    k_gemm<true, true><<<dim3(FF / 256, CAP / 256, NEXP), 512, 0, stream>>>(
        TbY, tok_map, WT, b1, Hm, HDIM, FF);
    k_transpose<<<dim3(FF / 64, HDIM / 64, NEXP), 256, 0, stream>>>(W2, WT, FF, HDIM);
    k_gemm<false, false><<<dim3(HDIM / 256, CAP / 256, NEXP), 512, 0, stream>>>(
        Hm, nullptr, WT, b2, TbY, FF, HDIM);
    k_combine<<<dim3(NTOK), 256, 0, stream>>>(TbY, dest, probs, out);
}

// Round 4
// 756.548 us; speedup vs baseline: 1.1447x; 1.0012x over previous
//
#include <hip/hip_runtime.h>
#include <hip/hip_bf16.h>
#include <math.h>

// Problem constants (reference: N=8192, H=2048, E=8, K=2, CF=1.25)
#define NTOK 8192
#define HDIM 2048
#define NEXP 8
#define TOPK 2
#define CAP  1280            // ceil(1.25 * 8192 / 8)
#define FF   4096            // 2*H

typedef float  f32x4  __attribute__((ext_vector_type(4)));
typedef __bf16 bf16x8 __attribute__((ext_vector_type(8)));

typedef __attribute__((address_space(1))) const unsigned int gas_u32;
typedef __attribute__((address_space(3))) unsigned int las_u32;

__device__ __forceinline__ void gload16(const void* g, void* l) {
    // async global -> LDS, 16 B per lane; LDS dest = wave-uniform base + lane*16
    __builtin_amdgcn_global_load_lds((gas_u32*)g, (las_u32*)l, 16, 0, 0);
}

__device__ __forceinline__ ushort f2bf(float f) {
    union { float f; unsigned u; } c; c.f = f;
    unsigned u = c.u;
    unsigned r = (u + 0x7FFFu + ((u >> 16) & 1u)) >> 16;   // RNE
    return (ushort)r;
}
__device__ __forceinline__ float bf2f(ushort h) {
    union { unsigned u; float f; } c; c.u = ((unsigned)h) << 16;
    return c.f;
}

// ---------------- tokens f32 -> bf16 ----------------
__global__ void k_convert(const float* __restrict__ src, ushort* __restrict__ dst) {
    int i = (blockIdx.x * 256 + threadIdx.x) * 8;
    float4 a = *(const float4*)(src + i);
    float4 b = *(const float4*)(src + i + 4);
    uint4 o;
    o.x = (unsigned)f2bf(a.x) | ((unsigned)f2bf(a.y) << 16);
    o.y = (unsigned)f2bf(a.z) | ((unsigned)f2bf(a.w) << 16);
    o.z = (unsigned)f2bf(b.x) | ((unsigned)f2bf(b.y) << 16);
    o.w = (unsigned)f2bf(b.z) | ((unsigned)f2bf(b.w) << 16);
    *(uint4*)(dst + i) = o;
}

// ---------------- router: logits (f64 accum), top-2, softmax ----------------
__global__ void k_router(const float* __restrict__ tokens, const float* __restrict__ Wr,
                         const float* __restrict__ br, int* __restrict__ eids,
                         float* __restrict__ probs) {
    int wave = threadIdx.x >> 6, lane = threadIdx.x & 63;
    int t = blockIdx.x * 4 + wave;
    const float* tp = tokens + (size_t)t * HDIM;
    double acc[NEXP];
    #pragma unroll
    for (int e = 0; e < NEXP; ++e) acc[e] = 0.0;
    for (int j = 0; j < HDIM / 64; ++j) {
        float x = tp[j * 64 + lane];
        #pragma unroll
        for (int e = 0; e < NEXP; ++e)
            acc[e] += (double)x * (double)Wr[e * HDIM + j * 64 + lane];
    }
    #pragma unroll
    for (int e = 0; e < NEXP; ++e) {
        #pragma unroll
        for (int off = 32; off; off >>= 1) acc[e] += __shfl_xor(acc[e], off, 64);
    }
    if (lane == 0) {
        float lg[NEXP];
        #pragma unroll
        for (int e = 0; e < NEXP; ++e) lg[e] = (float)acc[e] + br[e];
        int e0 = 0; float s0 = lg[0];
        #pragma unroll
        for (int e = 1; e < NEXP; ++e) if (lg[e] > s0) { s0 = lg[e]; e0 = e; }
        int e1 = -1; float s1 = -1e30f;
        #pragma unroll
        for (int e = 0; e < NEXP; ++e) if (e != e0 && lg[e] > s1) { s1 = lg[e]; e1 = e; }
        float ex = expf(s1 - s0);
        float den = 1.f + ex;
        eids[t * 2] = e0; eids[t * 2 + 1] = e1;
        probs[t * 2] = 1.f / den; probs[t * 2 + 1] = ex / den;
    }
}

// ---------------- deterministic rank/capacity assignment (1 block, 1 wave) ----------------
__global__ void k_assign(const int* __restrict__ eids, int* __restrict__ tok_map,
                         int* __restrict__ dest) {
    __shared__ int cnt[64][NEXP];
    int l = threadIdx.x;                           // 64 threads
    for (int i = l; i < NEXP * CAP; i += 64) tok_map[i] = 0;   // default token 0 (weight 0)
    int c[NEXP];
    #pragma unroll
    for (int e = 0; e < NEXP; ++e) c[e] = 0;
    const int base = l * 256;                      // 64 * 256 = 16384 = NTOK*TOPK
    for (int i = 0; i < 256; ++i) {
        int ee = eids[base + i];
        #pragma unroll
        for (int e = 0; e < NEXP; ++e) c[e] += (ee == e);
    }
    #pragma unroll
    for (int e = 0; e < NEXP; ++e) cnt[l][e] = c[e];
    __syncthreads();
    if (l < NEXP) {                                // exclusive scan over 64 chunks
        int run = 0;
        for (int b = 0; b < 64; ++b) { int v = cnt[b][l]; cnt[b][l] = run; run += v; }
    }
    __syncthreads();
    int off[NEXP];
    #pragma unroll
    for (int e = 0; e < NEXP; ++e) off[e] = cnt[l][e];
    for (int i = 0; i < 256; ++i) {
        int d = base + i;
        int ee = eids[d];
        int r = -1;
        #pragma unroll
        for (int e = 0; e < NEXP; ++e) { bool m = (ee == e); if (m) r = off[e]; off[e] += m; }
        if (r < CAP) { tok_map[ee * CAP + r] = d >> 1; dest[d] = ee * CAP + r; }
        else dest[d] = -1;
    }
}

// ---------------- W [E][Kd][Nd] f32 -> WT [E][Nd][Kd] bf16, 64x64 tiles ----------------
__global__ __launch_bounds__(256) void k_transpose(const float* __restrict__ src,
                                                   ushort* __restrict__ dst,
                                                   int Kd, int Nd) {
    __shared__ float tl[64][65];
    int e = blockIdx.z;
    int k0 = blockIdx.x * 64, n0 = blockIdx.y * 64;
    const float* s = src + (size_t)e * Kd * Nd;
    ushort* d = dst + (size_t)e * Kd * Nd;
    int tid = threadIdx.x;
    #pragma unroll
    for (int i = 0; i < 4; ++i) {
        int flat = (i * 256 + tid) * 4;            // 0..4092, nn multiple of 4
        int kk = flat >> 6, nn = flat & 63;
        float4 v = *(const float4*)(s + (size_t)(k0 + kk) * Nd + n0 + nn);
        tl[kk][nn] = v.x; tl[kk][nn + 1] = v.y; tl[kk][nn + 2] = v.z; tl[kk][nn + 3] = v.w;
    }
    __syncthreads();
    #pragma unroll
    for (int g = 0; g < 4; ++g) {
        int flat = g * 1024 + tid * 4;             // kk multiple of 4
        int nn = flat >> 6, kk = flat & 63;
        uint2 o;
        o.x = (unsigned)f2bf(tl[kk][nn])     | ((unsigned)f2bf(tl[kk + 1][nn]) << 16);
        o.y = (unsigned)f2bf(tl[kk + 2][nn]) | ((unsigned)f2bf(tl[kk + 3][nn]) << 16);
        *(uint2*)(d + (size_t)(n0 + nn) * Kd + k0 + kk) = o;
    }
}

// ---------------- grouped bf16 MFMA GEMM, 256x256 8-phase (m201 structure) ----------------
// C = act(A . B^T + bias). A: rows of Kd bf16 (via tmap if GATHER, else slot rows).
// B: [E][Nd][Kd] bf16 (K-contiguous). C: [E][CAP][Nd] bf16.
// 8 waves (2M x 4N), per-wave out 128x64. BK=64. LDS 128 KiB:
//   A: buf*32768 + half*16384  (even K-tile -> buf0, odd -> buf1; static)
//   B: 65536 + same. Each half = [128 rows][64 k] bf16, row stride 128 B.
// XOR-swizzle (G4): LDS byte-in-row ^= (row&7)<<4, realized as linear LDS dest +
// inverse-swizzled GLOBAL source (involution) + swizzled ds_read address.
// Staging clusters at phases 1/3/5/7; vmcnt(4) at phases 4,8 only.
// Fence discipline (rule 18 / m201): __builtin_amdgcn_s_barrier (no implicit drain),
// explicit lgkmcnt(0) + sched_barrier(0) between pre-MMA barrier and MFMA cluster,
// sched_barrier(0) after MMA and after counted vmcnt so phases cannot be deformed.
#define BAR()    __builtin_amdgcn_s_barrier()
#define SCHED0() __builtin_amdgcn_sched_barrier(0)
#define LGKM0()  do { asm volatile("s_waitcnt lgkmcnt(0)" ::: "memory"); SCHED0(); } while (0)
#define VMC4()   do { asm volatile("s_waitcnt vmcnt(4)" ::: "memory"); SCHED0(); } while (0)

template<bool DOGELU, bool GATHER>
__global__ __launch_bounds__(512, 2) void k_gemm(const ushort* __restrict__ A,
                                                 const int* __restrict__ tmap,
                                                 const ushort* __restrict__ B,
                                                 const float* __restrict__ bias,
                                                 ushort* __restrict__ C,
                                                 int Kd, int Nd) {
    __shared__ char lds[131072];
    const int tid  = threadIdx.x;
    const int lane = tid & 63;
    const int wave = tid >> 6;                    // 0..7
    const int wr = wave >> 2, wc = wave & 3;      // 2 x 4 wave grid
    const int e = blockIdx.z;
    const int bm0 = blockIdx.y * 256, bn0 = blockIdx.x * 256;

    // ---------- staging setup ----------
    const int srow = tid >> 3;                    // 0..63 within a 64-row group
    const int swzc = (tid ^ (tid >> 3)) & 7;      // inverse-swizzled 16B chunk (involution)
    const ushort* Be = B + (size_t)e * (size_t)Nd * Kd;
    const ushort* pa[4]; const ushort* pb[4];
    #pragma unroll
    for (int h = 0; h < 2; ++h)
        #pragma unroll
        for (int j = 0; j < 2; ++j) {
            int mrow = bm0 + h * 128 + j * 64 + srow;
            int arow = GATHER ? tmap[e * CAP + mrow] : (e * CAP + mrow);
            pa[h * 2 + j] = A  + (size_t)arow * Kd + swzc * 8;
            pb[h * 2 + j] = Be + (size_t)(bn0 + h * 128 + j * 64 + srow) * Kd + swzc * 8;
        }
    const int ldsW = wave * 1024;                 // wave-uniform lane block

    // ---------- compute-side fragment addressing ----------
    const int fr = lane & 15, kq = lane >> 4;     // frag row/col, k-quarter
    const int x0 = ((kq ^ (fr & 7)) * 16);        // swizzled 16B chunk byte, ks=0
    const int sA = wr * 16384 + fr * 128;                              // A: half = wr
    const int sB = 65536 + (wc >> 1) * 16384 + ((wc & 1) * 64 + fr) * 128; // B: half = wc>>1

    f32x4  acc[8][4] = {};
    bf16x8 bfr[4][2];                             // all 4 B n-frags x 2 k-slices live

    auto STAGE_A = [&](int b, int kt) {
        #pragma unroll
        for (int hj = 0; hj < 4; ++hj)
            gload16(pa[hj] + (size_t)kt * 64,
                    lds + b * 32768 + (hj >> 1) * 16384 + (hj & 1) * 8192 + ldsW);
    };
    auto STAGE_B = [&](int b, int kt) {
        #pragma unroll
        for (int hj = 0; hj < 4; ++hj)
            gload16(pb[hj] + (size_t)kt * 64,
                    lds + 65536 + b * 32768 + (hj >> 1) * 16384 + (hj & 1) * 8192 + ldsW);
    };
    auto LDA_ = [&](bf16x8 (&af)[4][2], int b, int mh) {
        #pragma unroll
        for (int m = 0; m < 4; ++m)
            #pragma unroll
            for (int ks = 0; ks < 2; ++ks)
                af[m][ks] = *(const bf16x8*)(lds + b * 32768 + sA + (mh * 4 + m) * 2048
                                             + (x0 ^ (ks << 6)));
    };
    auto LDB2 = [&](int b, int nh) {
        #pragma unroll
        for (int n = 0; n < 2; ++n)
            #pragma unroll
            for (int ks = 0; ks < 2; ++ks)
                bfr[nh * 2 + n][ks] = *(const bf16x8*)(lds + b * 32768 + sB
                                                       + (nh * 2 + n) * 2048 + (x0 ^ (ks << 6)));
    };
    auto MMA = [&](bf16x8 (&af)[4][2], int mh, int nh) {
        __builtin_amdgcn_s_setprio(1);
        #pragma unroll
        for (int m = 0; m < 4; ++m)
            #pragma unroll
            for (int n = 0; n < 2; ++n)
                #pragma unroll
                for (int ks = 0; ks < 2; ++ks)
                    acc[mh * 4 + m][nh * 2 + n] = __builtin_amdgcn_mfma_f32_16x16x32_bf16(
                        af[m][ks], bfr[nh * 2 + n][ks], acc[mh * 4 + m][nh * 2 + n], 0, 0, 0);
        __builtin_amdgcn_s_setprio(0);
        SCHED0();
    };

    const int NT  = Kd >> 6;                      // K-tiles (even for both GEMMs)
    const int nt2 = NT >> 1;                      // iterations (2 K-tiles each)

    // ---------- prologue: A(0),B(0) -> buf0; B(1) -> buf1 ----------
    STAGE_A(0, 0); STAGE_B(0, 0); STAGE_B(1, 1);
    VMC4();                                        // A(0),B(0) landed; B(1) in flight
    BAR();

    for (int it = 0; it < nt2; ++it) {
        const int kt1  = 2 * it + 1;
        const int ktN  = min(2 * it + 2, NT - 1);  // next even tile (clamped on last iter)
        const int ktN1 = min(2 * it + 3, NT - 1);  // next odd tile
        bf16x8 af[4][2];
        // ph1: tile kt0(buf0) quadrant (0,0); stage A(kt1)->buf1
        LDA_(af, 0, 0); LDB2(0, 0);
        STAGE_A(1, kt1);
        BAR(); LGKM0(); MMA(af, 0, 0); BAR();
        // ph2: quadrant (0,1)
        LDB2(0, 1);
        BAR(); LGKM0(); MMA(af, 0, 1); BAR();
        // ph3: quadrant (1,0); stage B(ktN)->buf0 (B-buf0 consumed at ph2)
        LDA_(af, 0, 1);
        STAGE_B(0, ktN);
        BAR(); LGKM0(); MMA(af, 1, 0); BAR();
        // ph4: quadrant (1,1); confirm A(kt1),B(kt1) landed for ph5-8
        VMC4();
        BAR(); LGKM0(); MMA(af, 1, 1); BAR();
        // ph5: tile kt1(buf1) quadrant (0,0); stage A(ktN)->buf0 (A-buf0 consumed at ph3)
        LDA_(af, 1, 0); LDB2(1, 0);
        STAGE_A(0, ktN);
        BAR(); LGKM0(); MMA(af, 0, 0); BAR();
        // ph6: quadrant (0,1)
        LDB2(1, 1);
        BAR(); LGKM0(); MMA(af, 0, 1); BAR();
        // ph7: quadrant (1,0); stage B(ktN1)->buf1 (B-buf1 consumed at ph6)
        LDA_(af, 1, 1);
        STAGE_B(1, ktN1);
        BAR(); LGKM0(); MMA(af, 1, 0); BAR();
        // ph8: quadrant (1,1); confirm B(ktN),A(ktN) landed for next ph1-4
        VMC4();
        BAR(); LGKM0(); MMA(af, 1, 1); BAR();
    }

    // ---------- epilogue ----------
    const float* be = bias + e * Nd;
    ushort* Ce = C + (size_t)e * CAP * Nd;
    const int rl = (lane >> 4) * 4, cl = lane & 15;
    #pragma unroll
    for (int ni = 0; ni < 4; ++ni) {
        int gc = bn0 + wc * 64 + ni * 16 + cl;
        float bv = be[gc];
        #pragma unroll
        for (int mi = 0; mi < 8; ++mi) {
            #pragma unroll
            for (int r = 0; r < 4; ++r) {
                int gr = bm0 + wr * 128 + mi * 16 + rl + r;
                float v = acc[mi][ni][r] + bv;
                if (DOGELU) v = 0.5f * v * (1.f + erff(v * 0.70710678118654752f));
                Ce[(size_t)gr * Nd + gc] = f2bf(v);
            }
        }
    }
}

// ---------------- deterministic combine: out[t] = sum_k p_k * Y[dest_k] ----------------
__global__ void k_combine(const ushort* __restrict__ Y, const int* __restrict__ dest,
                          const float* __restrict__ probs, float* __restrict__ out) {
    int t = blockIdx.x;
    int h0 = threadIdx.x * 8;
    int d0 = dest[t * 2], d1 = dest[t * 2 + 1];
    float p0 = d0 >= 0 ? probs[t * 2] : 0.f;
    float p1 = d1 >= 0 ? probs[t * 2 + 1] : 0.f;
    int r0 = d0 >= 0 ? d0 : 0, r1 = d1 >= 0 ? d1 : 0;
    uint4 a = *(const uint4*)(Y + (size_t)r0 * HDIM + h0);
    uint4 b = *(const uint4*)(Y + (size_t)r1 * HDIM + h0);
    float4 o0, o1;
    o0.x = p0 * bf2f(a.x & 0xffff) + p1 * bf2f(b.x & 0xffff);
    o0.y = p0 * bf2f(a.x >> 16)    + p1 * bf2f(b.x >> 16);
    o0.z = p0 * bf2f(a.y & 0xffff) + p1 * bf2f(b.y & 0xffff);
    o0.w = p0 * bf2f(a.y >> 16)    + p1 * bf2f(b.y >> 16);
    o1.x = p0 * bf2f(a.z & 0xffff) + p1 * bf2f(b.z & 0xffff);
    o1.y = p0 * bf2f(a.z >> 16)    + p1 * bf2f(b.z >> 16);
    o1.z = p0 * bf2f(a.w & 0xffff) + p1 * bf2f(b.w & 0xffff);
    o1.w = p0 * bf2f(a.w >> 16)    + p1 * bf2f(b.w >> 16);
    float* op = out + (size_t)t * HDIM + h0;
    *(float4*)op = o0;
    *(float4*)(op + 4) = o1;
}

extern "C" void kernel_launch(void* const* d_in, const int* in_sizes, int n_in,
                              void* d_out, int out_size, void* d_ws, size_t ws_size,
                              hipStream_t stream) {
    const float* tokens = (const float*)d_in[0];
    const float* Wr     = (const float*)d_in[1];
    const float* br     = (const float*)d_in[2];
    const float* W1     = (const float*)d_in[3];
    const float* b1     = (const float*)d_in[4];
    const float* W2     = (const float*)d_in[5];
    const float* b2     = (const float*)d_in[6];
    float* out = (float*)d_out;
    char* ws = (char*)d_ws;

    // workspace layout (peak ~249 MiB, phase-ordered reuse)
    int*    eids    = (int*)(ws);                  //  64 KB
    float*  probs   = (float*)(ws + 65536);        //  64 KB
    int*    tok_map = (int*)(ws + 131072);         //  40 KB
    int*    dest    = (int*)(ws + 172032);         //  64 KB
    size_t off = 1u << 20;
    ushort* TbY = (ushort*)(ws + off);             // tokens bf16 (33.5 MB) then Y bf16 (41.9 MB)
    off += 41943040;
    ushort* Hm  = (ushort*)(ws + off);             // gelu hidden bf16, 83.9 MB
    off += 83886080;
    ushort* WT  = (ushort*)(ws + off);             // W1T then W2T bf16, 134.2 MB
    (void)in_sizes; (void)n_in; (void)out_size; (void)ws_size;

    k_convert<<<dim3(NTOK * HDIM / 2048), 256, 0, stream>>>(tokens, TbY);
    k_router<<<dim3(NTOK / 4), 256, 0, stream>>>(tokens, Wr, br, eids, probs);
    k_assign<<<dim3(1), 64, 0, stream>>>(eids, tok_map, dest);
    k_transpose<<<dim3(HDIM / 64, FF / 64, NEXP), 256, 0, stream>>>(W1, WT, HDIM, FF);
    k_gemm<true, true><<<dim3(FF / 256, CAP / 256, NEXP), 512, 0, stream>>>(
        TbY, tok_map, WT, b1, Hm, HDIM, FF);
    k_transpose<<<dim3(FF / 64, HDIM / 64, NEXP), 256, 0, stream>>>(W2, WT, FF, HDIM);
    k_gemm<false, false><<<dim3(HDIM / 256, CAP / 256, NEXP), 512, 0, stream>>>(
        Hm, nullptr, WT, b2, TbY, FF, HDIM);
    k_combine<<<dim3(NTOK), 256, 0, stream>>>(TbY, dest, probs, out);
}